// Round 9
// baseline (1010.615 us; speedup 1.0000x reference)
//
#include <hip/hip_runtime.h>
#include <hip/hip_bf16.h>

// ---- static problem config ----
// B=32, H=W=64, C=256, WS=8, SHIFT=4, NH=8, HD=32, N=64 tok/window,
// NW=64 windows/img, Bw=2048 windows, M = Bw*64 = 131072 token rows.

typedef __bf16 bf16;
typedef __bf16 bf16x8 __attribute__((ext_vector_type(8)));
typedef __bf16 bf16x4 __attribute__((ext_vector_type(4)));
typedef float  f32x4  __attribute__((ext_vector_type(4)));

#define M_TOK 131072

// ---------------- prep: transpose fp32 weight (K,N) -> bf16 (N,K) ----------------
__global__ __launch_bounds__(256) void transpose_w(const float* __restrict__ src,
                                                   bf16* __restrict__ dst,
                                                   int K, int N) {
    int idx = blockIdx.x * 256 + threadIdx.x;   // grid sized exactly K*N/256
    int k = idx / N, n = idx - k * N;
    dst[(size_t)n * K + k] = (bf16)src[idx];
}

// ---------------- prep: rel-pos bias table -> rpb[h][n][m] (8,64,64) f32 ----------------
__global__ __launch_bounds__(256) void build_rpb(const float* __restrict__ bt,
                                                 float* __restrict__ rpb) {
    int idx = blockIdx.x * 256 + threadIdx.x;   // 32768
    int h = idx >> 12, n = (idx >> 6) & 63, m = idx & 63;
    int ridx = ((n >> 3) - (m >> 3) + 7) * 15 + ((n & 7) - (m & 7) + 7);
    rpb[idx] = bt[ridx * 8 + h];
}

// ---------------- LayerNorm (C=256), one wave per token ----------------
template <int PERM>
__global__ __launch_bounds__(256) void ln_k(const float* __restrict__ x,
                                            const float* __restrict__ g,
                                            const float* __restrict__ bb,
                                            bf16* __restrict__ dst) {
    int t = blockIdx.x * 4 + (threadIdx.x >> 6);
    int lane = threadIdx.x & 63;
    size_t src;
    if (PERM) {
        int w = t >> 6, n = t & 63;
        int b = w >> 6, nw = w & 63;
        int r = ((nw >> 3) * 8 + (n >> 3) + 4) & 63;
        int c = ((nw & 7) * 8 + (n & 7) + 4) & 63;
        src = ((size_t)b * 4096 + r * 64 + c) * 256;
    } else {
        src = (size_t)t * 256;
    }
    float4 v = *(const float4*)&x[src + lane * 4];
    float s = v.x + v.y + v.z + v.w;
    float sq = v.x * v.x + v.y * v.y + v.z * v.z + v.w * v.w;
#pragma unroll
    for (int off = 1; off < 64; off <<= 1) {
        s += __shfl_xor(s, off);
        sq += __shfl_xor(sq, off);
    }
    float mean = s * (1.0f / 256.0f);
    float var = sq * (1.0f / 256.0f) - mean * mean;
    float rstd = rsqrtf(var + 1e-5f);
    float4 gg = *(const float4*)&g[lane * 4];
    float4 bv = *(const float4*)&bb[lane * 4];
    bf16x4 o;
    o[0] = (bf16)((v.x - mean) * rstd * gg.x + bv.x);
    o[1] = (bf16)((v.y - mean) * rstd * gg.y + bv.y);
    o[2] = (bf16)((v.z - mean) * rstd * gg.z + bv.z);
    o[3] = (bf16)((v.w - mean) * rstd * gg.w + bv.w);
    *(bf16x4*)&dst[(size_t)t * 256 + lane * 4] = o;
}

// fast exact-form GELU: x*Phi(x) ~= v * sigmoid(2c(v + 0.044715 v^3)), c=0.79788456
__device__ __forceinline__ float fast_gelu(float v) {
    float t = v * v;
    float w = __builtin_fmaf(0.044715f * t, v, v);
    float e = __expf(-1.5957691216057308f * w);
    return v * __builtin_amdgcn_rcpf(1.0f + e);
}

// ---------------- GEMM: C(M x NDIM) = A(M x KDIM) * Bt(NDIM x KDIM)^T ----------------
// BARRIER-FREE STREAMING K-LOOP: 128x128 tile, 4 waves (2x2), each wave 64x64.
// A and B fragments loaded straight global->VGPR (16B/lane, 64B segments; B hits
// L2 since weights are tiny), register double-buffer 1 K-step ahead, 16 MFMA per
// step, NO LDS/barriers until the epilogue. Swapped mfma(bfr, af): reg-dim = 4
// consecutive out-cols, lane-dim = token.
// EPILOGUE VIA LDS TRANSPOSE (32KB) + __syncthreads fences (R7-verified).
// EPI 0: +bias -> bf16 out                          [QKV]
// EPI 1: +bias +resid, window-reverse+unshift -> f32 [proj]
// EPI 2: +bias, fast GELU -> bf16                    [fc1]
// EPI 3: +bias, outf += v (float4 RMW)               [fc2]
template <int NDIM, int KDIM, int EPI>
__global__ __launch_bounds__(256) void gemm_k(const bf16* __restrict__ A,
                                              const bf16* __restrict__ Bt,
                                              const float* __restrict__ bias,
                                              bf16* __restrict__ outb,
                                              float* __restrict__ outf,
                                              const float* __restrict__ resid) {
    __shared__ __align__(16) bf16 SH[16384];  // 32KB, epilogue transpose only
    constexpr int NBN = NDIM / 128;
    constexpr int NK = KDIM / 32;
    const int tid = threadIdx.x;
    // XCD-aware bijective swizzle: nwg % 8 == 0 for all our grids.
    const int nwg = gridDim.x;
    const int flat = blockIdx.x;
    const int cpx = nwg >> 3;
    const int orig = (flat & 7) * cpx + (flat >> 3);
    const int bm = orig / NBN, bn = orig % NBN;

    const int lane = tid & 63, wid = tid >> 6;
    const int wr = wid >> 1, wc = wid & 1;
    const int lhi = lane >> 4, llo = lane & 15;

    f32x4 acc[4][4];
#pragma unroll
    for (int i = 0; i < 4; i++)
#pragma unroll
        for (int j = 0; j < 4; j++) acc[i][j] = f32x4{0.f, 0.f, 0.f, 0.f};

    // per-lane fragment base pointers: lane (llo,lhi) reads row (…+llo),
    // k-granule lhi*8 .. +8 (16B contiguous); frag row stride 16*KDIM.
    const bf16* Aw = A + (size_t)(bm * 128 + wr * 64 + llo) * KDIM + lhi * 8;
    const bf16* Bw = Bt + (size_t)(bn * 128 + wc * 64 + llo) * KDIM + lhi * 8;

    bf16x8 afc[4], bfc[4];
#pragma unroll
    for (int mi = 0; mi < 4; mi++)
        afc[mi] = *(const bf16x8*)(Aw + mi * 16 * KDIM);
#pragma unroll
    for (int ni = 0; ni < 4; ni++)
        bfc[ni] = *(const bf16x8*)(Bw + ni * 16 * KDIM);

#pragma unroll
    for (int ks = 0; ks < NK; ks++) {
        bf16x8 afn[4], bfn[4];
        if (ks + 1 < NK) {
#pragma unroll
            for (int mi = 0; mi < 4; mi++)
                afn[mi] = *(const bf16x8*)(Aw + (ks + 1) * 32 + mi * 16 * KDIM);
#pragma unroll
            for (int ni = 0; ni < 4; ni++)
                bfn[ni] = *(const bf16x8*)(Bw + (ks + 1) * 32 + ni * 16 * KDIM);
        }
#pragma unroll
        for (int mi = 0; mi < 4; mi++)
#pragma unroll
            for (int ni = 0; ni < 4; ni++)
                acc[mi][ni] = __builtin_amdgcn_mfma_f32_16x16x32_bf16(bfc[ni], afc[mi],
                                                                      acc[mi][ni], 0, 0, 0);
        if (ks + 1 < NK) {
#pragma unroll
            for (int mi = 0; mi < 4; mi++) afc[mi] = afn[mi];
#pragma unroll
            for (int ni = 0; ni < 4; ni++) bfc[ni] = bfn[ni];
        }
    }

    // frag (mi,ni) reg r: token = wr*64+mi*16+llo, col = wc*64+ni*16+lhi*4+r
    __syncthreads();
    char* shb = (char*)SH;
    if constexpr (EPI == 0 || EPI == 2) {
        // ---- bf16 tile 128x128 (32KB), unit-XOR swizzled ----
#pragma unroll
        for (int ni = 0; ni < 4; ni++) {
            const int lcol = wc * 64 + ni * 16 + lhi * 4;
            const float4 b4 = *(const float4*)&bias[bn * 128 + lcol];
#pragma unroll
            for (int mi = 0; mi < 4; mi++) {
                const int ltok = wr * 64 + mi * 16 + llo;
                float v0 = acc[mi][ni][0] + b4.x;
                float v1 = acc[mi][ni][1] + b4.y;
                float v2 = acc[mi][ni][2] + b4.z;
                float v3 = acc[mi][ni][3] + b4.w;
                bf16x4 o;
                if constexpr (EPI == 2) {
                    o[0] = (bf16)fast_gelu(v0); o[1] = (bf16)fast_gelu(v1);
                    o[2] = (bf16)fast_gelu(v2); o[3] = (bf16)fast_gelu(v3);
                } else {
                    o[0] = (bf16)v0; o[1] = (bf16)v1; o[2] = (bf16)v2; o[3] = (bf16)v3;
                }
                const int u2 = (lcol >> 3) ^ (ltok & 15);
                *(bf16x4*)(shb + ltok * 256 + u2 * 16 + (lcol & 7) * 2) = o;
            }
        }
        __syncthreads();
        const int j = lane & 15;
#pragma unroll
        for (int rnd = 0; rnd < 8; rnd++) {
            const int ltok = wid * 32 + rnd * 4 + (lane >> 4);
            const int u2 = j ^ (ltok & 15);
            bf16x8 v = *(const bf16x8*)(shb + ltok * 256 + u2 * 16);
            *(bf16x8*)&outb[(size_t)(bm * 128 + ltok) * NDIM + bn * 128 + j * 8] = v;
        }
    } else {
        // ---- f32, two 128x64 half-tiles (32KB each) ----
#pragma unroll
        for (int p = 0; p < 2; p++) {
            if (wc == p) {
#pragma unroll
                for (int ni = 0; ni < 4; ni++) {
                    const int lcolh = ni * 16 + lhi * 4;  // 0..63 within half
                    const float4 b4 = *(const float4*)&bias[bn * 128 + p * 64 + lcolh];
#pragma unroll
                    for (int mi = 0; mi < 4; mi++) {
                        const int ltok = wr * 64 + mi * 16 + llo;
                        float4 o = {acc[mi][ni][0] + b4.x, acc[mi][ni][1] + b4.y,
                                    acc[mi][ni][2] + b4.z, acc[mi][ni][3] + b4.w};
                        const int u2 = (lcolh >> 2) ^ (ltok & 15);
                        *(float4*)(shb + ltok * 256 + u2 * 16) = o;
                    }
                }
            }
            __syncthreads();
            const int j = lane & 15;
#pragma unroll
            for (int rnd = 0; rnd < 8; rnd++) {
                const int ltok = wid * 32 + rnd * 4 + (lane >> 4);
                const int u2 = j ^ (ltok & 15);
                float4 v = *(const float4*)(shb + ltok * 256 + u2 * 16);
                const int gcol = bn * 128 + p * 64 + j * 4;
                const int grow = bm * 128 + ltok;
                if constexpr (EPI == 1) {
                    int w = grow >> 6, n = grow & 63;
                    int b = w >> 6, nw = w & 63;
                    int rr = ((nw >> 3) * 8 + (n >> 3) + 4) & 63;
                    int cc = ((nw & 7) * 8 + (n & 7) + 4) & 63;
                    size_t dst = ((size_t)b * 4096 + rr * 64 + cc) * 256 + gcol;
                    float4 rs = *(const float4*)&resid[dst];
                    float4 o = {rs.x + v.x, rs.y + v.y, rs.z + v.z, rs.w + v.w};
                    *(float4*)&outf[dst] = o;
                } else {
                    size_t dst = (size_t)grow * NDIM + gcol;
                    float4 cur = *(const float4*)&outf[dst];
                    float4 o = {cur.x + v.x, cur.y + v.y, cur.z + v.z, cur.w + v.w};
                    *(float4*)&outf[dst] = o;
                }
            }
            if (p == 0) __syncthreads();
        }
    }
}

// ---------------- windowed attention: one wave per (window, head) ----------------
__device__ __forceinline__ int regid3(int p) { return p < 56 ? 0 : (p < 60 ? 1 : 2); }

__global__ __launch_bounds__(256) void attn_k(const bf16* __restrict__ qkv,
                                              const float* __restrict__ rpb,
                                              bf16* __restrict__ aout) {
    __shared__ __align__(16) bf16 Pl[4][64 * 80];
    const int wid = threadIdx.x >> 6, lane = threadIdx.x & 63;
    const int lhi = lane >> 4, llo = lane & 15;
    const int wh = blockIdx.x * 4 + wid;
    const int w = wh >> 3, h = wh & 7;
    const bf16* base = qkv + (size_t)w * (64 * 768);

    // --- S = scale*Q K^T + rpb + mask ---
    bf16x8 qf[4], kf[4];
#pragma unroll
    for (int i = 0; i < 4; i++)
        qf[i] = *(const bf16x8*)(base + (i * 16 + llo) * 768 + h * 32 + lhi * 8);
#pragma unroll
    for (int i = 0; i < 4; i++)
        kf[i] = *(const bf16x8*)(base + (i * 16 + llo) * 768 + 256 + h * 32 + lhi * 8);
    f32x4 s[4][4];
#pragma unroll
    for (int mi = 0; mi < 4; mi++)
#pragma unroll
        for (int ni = 0; ni < 4; ni++) {
            s[mi][ni] = f32x4{0.f, 0.f, 0.f, 0.f};
            s[mi][ni] =
                __builtin_amdgcn_mfma_f32_16x16x32_bf16(qf[mi], kf[ni], s[mi][ni], 0, 0, 0);
        }

    const int nw = w & 63;
    const int pr0 = (nw >> 3) * 8, pc0 = (nw & 7) * 8;
    int creg[4];
#pragma unroll
    for (int ni = 0; ni < 4; ni++) {
        int m = ni * 16 + llo;
        creg[ni] = regid3(pr0 + (m >> 3)) * 3 + regid3(pc0 + (m & 7));
    }
    float rmax[4][4], rsum[4][4];
#pragma unroll
    for (int mi = 0; mi < 4; mi++)
#pragma unroll
        for (int r = 0; r < 4; r++) {
            int n = mi * 16 + lhi * 4 + r;
            int rreg = regid3(pr0 + (n >> 3)) * 3 + regid3(pc0 + (n & 7));
            float mx = -1e30f;
#pragma unroll
            for (int ni = 0; ni < 4; ni++) {
                int m = ni * 16 + llo;
                float sv = s[mi][ni][r] * 0.17677669529663687f + rpb[(h * 64 + n) * 64 + m] +
                           (rreg == creg[ni] ? 0.0f : -100.0f);
                s[mi][ni][r] = sv;
                mx = fmaxf(mx, sv);
            }
            rmax[mi][r] = mx;
        }
#pragma unroll
    for (int off = 1; off < 16; off <<= 1)
#pragma unroll
        for (int mi = 0; mi < 4; mi++)
#pragma unroll
            for (int r = 0; r < 4; r++)
                rmax[mi][r] = fmaxf(rmax[mi][r], __shfl_xor(rmax[mi][r], off));
#pragma unroll
    for (int mi = 0; mi < 4; mi++)
#pragma unroll
        for (int r = 0; r < 4; r++) {
            float a = 0.f;
#pragma unroll
            for (int ni = 0; ni < 4; ni++) {
                float p = __expf(s[mi][ni][r] - rmax[mi][r]);
                s[mi][ni][r] = p;
                a += p;
            }
            rsum[mi][r] = a;
        }
#pragma unroll
    for (int off = 1; off < 16; off <<= 1)
#pragma unroll
        for (int mi = 0; mi < 4; mi++)
#pragma unroll
            for (int r = 0; r < 4; r++) rsum[mi][r] += __shfl_xor(rsum[mi][r], off);

    // normalized P -> LDS (re-fragment for PV)
    bf16* P = Pl[wid];
#pragma unroll
    for (int mi = 0; mi < 4; mi++)
#pragma unroll
        for (int r = 0; r < 4; r++) {
            float rinv = 1.0f / rsum[mi][r];
            int row = mi * 16 + lhi * 4 + r;
#pragma unroll
            for (int ni = 0; ni < 4; ni++)
                P[row * 80 + ni * 16 + llo] = (bf16)(s[mi][ni][r] * rinv);
        }

    // --- O = P V ---
    f32x4 o[4][2];
#pragma unroll
    for (int mi = 0; mi < 4; mi++)
#pragma unroll
        for (int ni = 0; ni < 2; ni++) o[mi][ni] = f32x4{0.f, 0.f, 0.f, 0.f};
#pragma unroll
    for (int kc = 0; kc < 2; kc++) {
        bf16x8 pf[4], vf[2];
#pragma unroll
        for (int mi = 0; mi < 4; mi++)
            pf[mi] = *(const bf16x8*)(P + (mi * 16 + llo) * 80 + kc * 32 + lhi * 8);
#pragma unroll
        for (int ni = 0; ni < 2; ni++)
#pragma unroll
            for (int j = 0; j < 8; j++)
                vf[ni][j] = base[(kc * 32 + lhi * 8 + j) * 768 + 512 + h * 32 + ni * 16 + llo];
#pragma unroll
        for (int mi = 0; mi < 4; mi++)
#pragma unroll
            for (int ni = 0; ni < 2; ni++)
                o[mi][ni] =
                    __builtin_amdgcn_mfma_f32_16x16x32_bf16(pf[mi], vf[ni], o[mi][ni], 0, 0, 0);
    }
#pragma unroll
    for (int mi = 0; mi < 4; mi++)
#pragma unroll
        for (int ni = 0; ni < 2; ni++)
#pragma unroll
            for (int r = 0; r < 4; r++) {
                int row = mi * 16 + lhi * 4 + r;
                aout[(size_t)(w * 64 + row) * 256 + h * 32 + ni * 16 + llo] =
                    (bf16)o[mi][ni][r];
            }
}

// ---------------- launcher ----------------
extern "C" void kernel_launch(void* const* d_in, const int* in_sizes, int n_in,
                              void* d_out, int out_size, void* d_ws, size_t ws_size,
                              hipStream_t stream) {
    const float* x      = (const float*)d_in[0];
    const float* n1g    = (const float*)d_in[1];
    const float* n1b    = (const float*)d_in[2];
    const float* qkv_w  = (const float*)d_in[3];
    const float* qkv_b  = (const float*)d_in[4];
    const float* proj_w = (const float*)d_in[5];
    const float* proj_b = (const float*)d_in[6];
    const float* btab   = (const float*)d_in[7];
    const float* n2g    = (const float*)d_in[8];
    const float* n2b    = (const float*)d_in[9];
    const float* fc1_w  = (const float*)d_in[10];
    const float* fc1_b  = (const float*)d_in[11];
    const float* fc2_w  = (const float*)d_in[12];
    const float* fc2_b  = (const float*)d_in[13];
    float* out = (float*)d_out;
    char* ws = (char*)d_ws;

    // workspace layout (bytes)
    constexpr size_t o_xw   = 0;
    constexpr size_t o_qkv  = 67108864ull;
    constexpr size_t o_attn = 268435456ull;
    constexpr size_t o_g    = 0;                    // G reuses XW+QKV
    constexpr size_t o_h    = 268435456ull;         // H bf16 reuses ATTN slot
    constexpr size_t o_wq   = 335544320ull;
    constexpr size_t o_wp   = o_wq + 393216;
    constexpr size_t o_w1   = o_wp + 131072;
    constexpr size_t o_w2   = o_w1 + 524288;
    constexpr size_t o_rpb  = o_w2 + 524288;

    bf16* XW   = (bf16*)(ws + o_xw);
    bf16* QKV  = (bf16*)(ws + o_qkv);
    bf16* ATTN = (bf16*)(ws + o_attn);
    bf16* G    = (bf16*)(ws + o_g);
    bf16* Hb   = (bf16*)(ws + o_h);
    bf16* WQ   = (bf16*)(ws + o_wq);
    bf16* WP   = (bf16*)(ws + o_wp);
    bf16* W1   = (bf16*)(ws + o_w1);
    bf16* W2   = (bf16*)(ws + o_w2);
    float* RPB = (float*)(ws + o_rpb);

    dim3 blk(256);
    // prep
    transpose_w<<<768, blk, 0, stream>>>(qkv_w, WQ, 256, 768);
    transpose_w<<<256, blk, 0, stream>>>(proj_w, WP, 256, 256);
    transpose_w<<<1024, blk, 0, stream>>>(fc1_w, W1, 256, 1024);
    transpose_w<<<1024, blk, 0, stream>>>(fc2_w, W2, 1024, 256);
    build_rpb<<<128, blk, 0, stream>>>(btab, RPB);

    // LN1 + shift + window partition
    ln_k<1><<<M_TOK / 4, blk, 0, stream>>>(x, n1g, n1b, XW);
    // QKV  (grid flattened: nwg = 6*1024)
    gemm_k<768, 256, 0><<<6 * 1024, blk, 0, stream>>>(XW, WQ, qkv_b, QKV, nullptr, nullptr);
    // attention
    attn_k<<<4096, blk, 0, stream>>>(QKV, RPB, ATTN);
    // proj + reverse + unshift + residual -> d_out (x1)
    gemm_k<256, 256, 1><<<2 * 1024, blk, 0, stream>>>(ATTN, WP, proj_b, nullptr, out, x);
    // LN2
    ln_k<0><<<M_TOK / 4, blk, 0, stream>>>(out, n2g, n2b, Hb);
    // FC1 + GELU
    gemm_k<1024, 256, 2><<<8 * 1024, blk, 0, stream>>>(Hb, W1, fc1_b, G, nullptr, nullptr);
    // FC2 + residual accumulate
    gemm_k<256, 1024, 3><<<2 * 1024, blk, 0, stream>>>(G, W2, fc2_b, nullptr, out, nullptr);
}

// Round 10
// 584.859 us; speedup vs baseline: 1.7280x; 1.7280x over previous
//
#include <hip/hip_runtime.h>
#include <hip/hip_bf16.h>

// ---- static problem config ----
// B=32, H=W=64, C=256, WS=8, SHIFT=4, NH=8, HD=32, N=64 tok/window,
// NW=64 windows/img, Bw=2048 windows, M = Bw*64 = 131072 token rows.

typedef __bf16 bf16;
typedef __bf16 bf16x8 __attribute__((ext_vector_type(8)));
typedef __bf16 bf16x4 __attribute__((ext_vector_type(4)));
typedef float  f32x4  __attribute__((ext_vector_type(4)));

#define M_TOK 131072

#define GLDS(gp, lp)                                                                   \
    __builtin_amdgcn_global_load_lds(                                                  \
        (const __attribute__((address_space(1))) unsigned int*)(gp),                   \
        (__attribute__((address_space(3))) unsigned int*)(lp), 16, 0, 0)

// ---------------- prep: transpose fp32 weight (K,N) -> bf16 (N,K) ----------------
__global__ __launch_bounds__(256) void transpose_w(const float* __restrict__ src,
                                                   bf16* __restrict__ dst,
                                                   int K, int N) {
    int idx = blockIdx.x * 256 + threadIdx.x;   // grid sized exactly K*N/256
    int k = idx / N, n = idx - k * N;
    dst[(size_t)n * K + k] = (bf16)src[idx];
}

// ---------------- prep: rel-pos bias table -> rpb[h][n][m] (8,64,64) f32 ----------------
__global__ __launch_bounds__(256) void build_rpb(const float* __restrict__ bt,
                                                 float* __restrict__ rpb) {
    int idx = blockIdx.x * 256 + threadIdx.x;   // 32768
    int h = idx >> 12, n = (idx >> 6) & 63, m = idx & 63;
    int ridx = ((n >> 3) - (m >> 3) + 7) * 15 + ((n & 7) - (m & 7) + 7);
    rpb[idx] = bt[ridx * 8 + h];
}

// ---------------- LayerNorm (C=256), one wave per token ----------------
template <int PERM>
__global__ __launch_bounds__(256) void ln_k(const float* __restrict__ x,
                                            const float* __restrict__ g,
                                            const float* __restrict__ bb,
                                            bf16* __restrict__ dst) {
    int t = blockIdx.x * 4 + (threadIdx.x >> 6);
    int lane = threadIdx.x & 63;
    size_t src;
    if (PERM) {
        int w = t >> 6, n = t & 63;
        int b = w >> 6, nw = w & 63;
        int r = ((nw >> 3) * 8 + (n >> 3) + 4) & 63;
        int c = ((nw & 7) * 8 + (n & 7) + 4) & 63;
        src = ((size_t)b * 4096 + r * 64 + c) * 256;
    } else {
        src = (size_t)t * 256;
    }
    float4 v = *(const float4*)&x[src + lane * 4];
    float s = v.x + v.y + v.z + v.w;
    float sq = v.x * v.x + v.y * v.y + v.z * v.z + v.w * v.w;
#pragma unroll
    for (int off = 1; off < 64; off <<= 1) {
        s += __shfl_xor(s, off);
        sq += __shfl_xor(sq, off);
    }
    float mean = s * (1.0f / 256.0f);
    float var = sq * (1.0f / 256.0f) - mean * mean;
    float rstd = rsqrtf(var + 1e-5f);
    float4 gg = *(const float4*)&g[lane * 4];
    float4 bv = *(const float4*)&bb[lane * 4];
    bf16x4 o;
    o[0] = (bf16)((v.x - mean) * rstd * gg.x + bv.x);
    o[1] = (bf16)((v.y - mean) * rstd * gg.y + bv.y);
    o[2] = (bf16)((v.z - mean) * rstd * gg.z + bv.z);
    o[3] = (bf16)((v.w - mean) * rstd * gg.w + bv.w);
    *(bf16x4*)&dst[(size_t)t * 256 + lane * 4] = o;
}

// fast exact-form GELU: x*Phi(x) ~= v * sigmoid(2c(v + 0.044715 v^3)), c=0.79788456
__device__ __forceinline__ float fast_gelu(float v) {
    float t = v * v;
    float w = __builtin_fmaf(0.044715f * t, v, v);
    float e = __expf(-1.5957691216057308f * w);
    return v * __builtin_amdgcn_rcpf(1.0f + e);
}

// ---------------- GEMM: C(M x NDIM) = A(M x KDIM) * Bt(NDIM x KDIM)^T ----------------
// (R8 structure, verified) 128x128 tile, BK=32, 4 waves (2x2), 3-deep LDS pipeline
// (48KB), global_load_lds w=16, counted vmcnt; swapped mfma(bfr, af);
// LDS-transpose epilogue with __syncthreads fences.
// EPI 0: +bias -> bf16 out                          [QKV]
// EPI 1: +bias +resid, window-reverse+unshift -> f32 [proj]
// EPI 2: +bias, fast GELU -> bf16                    [fc1]
// EPI 3: +bias, outf += v (float4 RMW)               [fc2]
template <int NDIM, int KDIM, int EPI>
__global__ __launch_bounds__(256) void gemm_k(const bf16* __restrict__ A,
                                              const bf16* __restrict__ Bt,
                                              const float* __restrict__ bias,
                                              bf16* __restrict__ outb,
                                              float* __restrict__ outf,
                                              const float* __restrict__ resid) {
    __shared__ __align__(16) bf16 SH[24576];  // 48KB: A 3x8KB | B 3x8KB
    constexpr int NBN = NDIM / 128;
    constexpr int NK = KDIM / 32;
    static_assert(NK >= 3, "pipeline needs >=3 K-steps");
    const int tid = threadIdx.x;
    // XCD-aware bijective swizzle: nwg % 8 == 0 for all our grids.
    const int nwg = gridDim.x;
    const int flat = blockIdx.x;
    const int cpx = nwg >> 3;
    const int orig = (flat & 7) * cpx + (flat >> 3);
    const int bm = orig / NBN, bn = orig % NBN;

    const int lane = tid & 63, wid = tid >> 6;
    const int wr = wid >> 1, wc = wid & 1;
    const int lhi = lane >> 4, llo = lane & 15;

    f32x4 acc[4][4];
#pragma unroll
    for (int i = 0; i < 4; i++)
#pragma unroll
        for (int j = 0; j < 4; j++) acc[i][j] = f32x4{0.f, 0.f, 0.f, 0.f};

    // staging addresses: wave wid covers rows [wid*32, wid*32+32)
    const int srow = wid * 32 + (lane >> 2);
    // swizzled source granule: ((lane&3) - (row>>1))&3
    const int scol = (((lane & 3) - ((lane >> 3) & 3)) & 3) * 8;
    const bf16* Ap = A + (size_t)(bm * 128 + srow) * KDIM + scol;
    const bf16* Bp = Bt + (size_t)(bn * 128 + srow) * KDIM + scol;
    // swizzled read granule: (lhi + (row>>1))&3 == (lhi + (llo>>1))&3
    const int gsw = ((lhi + (llo >> 1)) & 3) * 8;

#define STAGE(bufidx)                                                                  \
    do {                                                                               \
        bf16* Al = SH + (bufidx)*4096 + wid * 1024;                                    \
        bf16* Bl = SH + 12288 + (bufidx)*4096 + wid * 1024;                            \
        GLDS(Ap, Al);                                                                  \
        GLDS(Ap + 16 * KDIM, Al + 16 * 32);                                            \
        GLDS(Bp, Bl);                                                                  \
        GLDS(Bp + 16 * KDIM, Bl + 16 * 32);                                            \
        Ap += 32;                                                                      \
        Bp += 32;                                                                      \
    } while (0)

#define COMPUTE(bufidx)                                                                \
    do {                                                                               \
        const int ab = (bufidx)*4096;                                                  \
        bf16x8 af[4], bfr[4];                                                          \
        _Pragma("unroll") for (int mi = 0; mi < 4; mi++) af[mi] =                      \
            *(const bf16x8*)&SH[ab + (wr * 64 + mi * 16 + llo) * 32 + gsw];            \
        _Pragma("unroll") for (int ni = 0; ni < 4; ni++) bfr[ni] =                     \
            *(const bf16x8*)&SH[12288 + ab + (wc * 64 + ni * 16 + llo) * 32 + gsw];    \
        _Pragma("unroll") for (int mi = 0; mi < 4; mi++)                               \
            _Pragma("unroll") for (int ni = 0; ni < 4; ni++) acc[mi][ni] =             \
                __builtin_amdgcn_mfma_f32_16x16x32_bf16(bfr[ni], af[mi],               \
                                                        acc[mi][ni], 0, 0, 0);         \
    } while (0)

#define WAITBAR(N)                                                                     \
    asm volatile("s_waitcnt vmcnt(" #N ")" ::: "memory");                              \
    __builtin_amdgcn_s_barrier();                                                      \
    __builtin_amdgcn_sched_barrier(0)

#define END_PHASE                                                                      \
    asm volatile("s_waitcnt lgkmcnt(0)" ::: "memory");                                 \
    __builtin_amdgcn_s_barrier();                                                      \
    __builtin_amdgcn_sched_barrier(0)

    // prologue: 3 tiles in flight
    STAGE(0);
    STAGE(1);
    STAGE(2);
    int buf = 0;
    for (int i = 0; i + 3 < NK; ++i) {
        WAITBAR(8);
        COMPUTE(buf);
        END_PHASE;
        STAGE(buf);
        buf = (buf == 2) ? 0 : buf + 1;
    }
    WAITBAR(8);
    COMPUTE(buf);
    buf = (buf == 2) ? 0 : buf + 1;
    WAITBAR(4);
    COMPUTE(buf);
    buf = (buf == 2) ? 0 : buf + 1;
    WAITBAR(0);
    COMPUTE(buf);

#undef STAGE
#undef COMPUTE
#undef WAITBAR
#undef END_PHASE

    // K-loop LDS reads drained before epilogue reuses SH (full fence)
    __syncthreads();

    // frag (mi,ni) reg r: token = wr*64+mi*16+llo, col = wc*64+ni*16+lhi*4+r
    char* shb = (char*)SH;
    if constexpr (EPI == 0 || EPI == 2) {
        // ---- bf16 tile 128x128 (32KB), unit-XOR swizzled ----
#pragma unroll
        for (int ni = 0; ni < 4; ni++) {
            const int lcol = wc * 64 + ni * 16 + lhi * 4;
            const float4 b4 = *(const float4*)&bias[bn * 128 + lcol];
#pragma unroll
            for (int mi = 0; mi < 4; mi++) {
                const int ltok = wr * 64 + mi * 16 + llo;
                float v0 = acc[mi][ni][0] + b4.x;
                float v1 = acc[mi][ni][1] + b4.y;
                float v2 = acc[mi][ni][2] + b4.z;
                float v3 = acc[mi][ni][3] + b4.w;
                bf16x4 o;
                if constexpr (EPI == 2) {
                    o[0] = (bf16)fast_gelu(v0); o[1] = (bf16)fast_gelu(v1);
                    o[2] = (bf16)fast_gelu(v2); o[3] = (bf16)fast_gelu(v3);
                } else {
                    o[0] = (bf16)v0; o[1] = (bf16)v1; o[2] = (bf16)v2; o[3] = (bf16)v3;
                }
                const int u2 = (lcol >> 3) ^ (ltok & 15);
                *(bf16x4*)(shb + ltok * 256 + u2 * 16 + (lcol & 7) * 2) = o;
            }
        }
        __syncthreads();
        const int j = lane & 15;
#pragma unroll
        for (int rnd = 0; rnd < 8; rnd++) {
            const int ltok = wid * 32 + rnd * 4 + (lane >> 4);
            const int u2 = j ^ (ltok & 15);
            bf16x8 v = *(const bf16x8*)(shb + ltok * 256 + u2 * 16);
            *(bf16x8*)&outb[(size_t)(bm * 128 + ltok) * NDIM + bn * 128 + j * 8] = v;
        }
    } else {
        // ---- f32, two 128x64 half-tiles (32KB each) ----
#pragma unroll
        for (int p = 0; p < 2; p++) {
            if (wc == p) {
#pragma unroll
                for (int ni = 0; ni < 4; ni++) {
                    const int lcolh = ni * 16 + lhi * 4;  // 0..63 within half
                    const float4 b4 = *(const float4*)&bias[bn * 128 + p * 64 + lcolh];
#pragma unroll
                    for (int mi = 0; mi < 4; mi++) {
                        const int ltok = wr * 64 + mi * 16 + llo;
                        float4 o = {acc[mi][ni][0] + b4.x, acc[mi][ni][1] + b4.y,
                                    acc[mi][ni][2] + b4.z, acc[mi][ni][3] + b4.w};
                        const int u2 = (lcolh >> 2) ^ (ltok & 15);
                        *(float4*)(shb + ltok * 256 + u2 * 16) = o;
                    }
                }
            }
            __syncthreads();
            const int j = lane & 15;
#pragma unroll
            for (int rnd = 0; rnd < 8; rnd++) {
                const int ltok = wid * 32 + rnd * 4 + (lane >> 4);
                const int u2 = j ^ (ltok & 15);
                float4 v = *(const float4*)(shb + ltok * 256 + u2 * 16);
                const int gcol = bn * 128 + p * 64 + j * 4;
                const int grow = bm * 128 + ltok;
                if constexpr (EPI == 1) {
                    int w = grow >> 6, n = grow & 63;
                    int b = w >> 6, nw = w & 63;
                    int rr = ((nw >> 3) * 8 + (n >> 3) + 4) & 63;
                    int cc = ((nw & 7) * 8 + (n & 7) + 4) & 63;
                    size_t dst = ((size_t)b * 4096 + rr * 64 + cc) * 256 + gcol;
                    float4 rs = *(const float4*)&resid[dst];
                    float4 o = {rs.x + v.x, rs.y + v.y, rs.z + v.z, rs.w + v.w};
                    *(float4*)&outf[dst] = o;
                } else {
                    size_t dst = (size_t)grow * NDIM + gcol;
                    float4 cur = *(const float4*)&outf[dst];
                    float4 o = {cur.x + v.x, cur.y + v.y, cur.z + v.z, cur.w + v.w};
                    *(float4*)&outf[dst] = o;
                }
            }
            if (p == 0) __syncthreads();
        }
    }
}

// ---------------- windowed attention: one wave per (window, head) ----------------
__device__ __forceinline__ int regid3(int p) { return p < 56 ? 0 : (p < 60 ? 1 : 2); }

// qkv points at a CHUNK of windows; woff is the global window offset of the chunk
// (only used for nothing — mask depends on w%64 which is chunk-invariant since
// chunks are whole images). aout is pre-offset by the caller.
__global__ __launch_bounds__(256) void attn_k(const bf16* __restrict__ qkv,
                                              const float* __restrict__ rpb,
                                              bf16* __restrict__ aout) {
    __shared__ __align__(16) bf16 Pl[4][64 * 80];
    const int wid = threadIdx.x >> 6, lane = threadIdx.x & 63;
    const int lhi = lane >> 4, llo = lane & 15;
    const int wh = blockIdx.x * 4 + wid;
    const int w = wh >> 3, h = wh & 7;
    const bf16* base = qkv + (size_t)w * (64 * 768);

    // --- S = scale*Q K^T + rpb + mask ---
    bf16x8 qf[4], kf[4];
#pragma unroll
    for (int i = 0; i < 4; i++)
        qf[i] = *(const bf16x8*)(base + (i * 16 + llo) * 768 + h * 32 + lhi * 8);
#pragma unroll
    for (int i = 0; i < 4; i++)
        kf[i] = *(const bf16x8*)(base + (i * 16 + llo) * 768 + 256 + h * 32 + lhi * 8);
    f32x4 s[4][4];
#pragma unroll
    for (int mi = 0; mi < 4; mi++)
#pragma unroll
        for (int ni = 0; ni < 4; ni++) {
            s[mi][ni] = f32x4{0.f, 0.f, 0.f, 0.f};
            s[mi][ni] =
                __builtin_amdgcn_mfma_f32_16x16x32_bf16(qf[mi], kf[ni], s[mi][ni], 0, 0, 0);
        }

    const int nw = w & 63;
    const int pr0 = (nw >> 3) * 8, pc0 = (nw & 7) * 8;
    int creg[4];
#pragma unroll
    for (int ni = 0; ni < 4; ni++) {
        int m = ni * 16 + llo;
        creg[ni] = regid3(pr0 + (m >> 3)) * 3 + regid3(pc0 + (m & 7));
    }
    float rmax[4][4], rsum[4][4];
#pragma unroll
    for (int mi = 0; mi < 4; mi++)
#pragma unroll
        for (int r = 0; r < 4; r++) {
            int n = mi * 16 + lhi * 4 + r;
            int rreg = regid3(pr0 + (n >> 3)) * 3 + regid3(pc0 + (n & 7));
            float mx = -1e30f;
#pragma unroll
            for (int ni = 0; ni < 4; ni++) {
                int m = ni * 16 + llo;
                float sv = s[mi][ni][r] * 0.17677669529663687f + rpb[(h * 64 + n) * 64 + m] +
                           (rreg == creg[ni] ? 0.0f : -100.0f);
                s[mi][ni][r] = sv;
                mx = fmaxf(mx, sv);
            }
            rmax[mi][r] = mx;
        }
#pragma unroll
    for (int off = 1; off < 16; off <<= 1)
#pragma unroll
        for (int mi = 0; mi < 4; mi++)
#pragma unroll
            for (int r = 0; r < 4; r++)
                rmax[mi][r] = fmaxf(rmax[mi][r], __shfl_xor(rmax[mi][r], off));
#pragma unroll
    for (int mi = 0; mi < 4; mi++)
#pragma unroll
        for (int r = 0; r < 4; r++) {
            float a = 0.f;
#pragma unroll
            for (int ni = 0; ni < 4; ni++) {
                float p = __expf(s[mi][ni][r] - rmax[mi][r]);
                s[mi][ni][r] = p;
                a += p;
            }
            rsum[mi][r] = a;
        }
#pragma unroll
    for (int off = 1; off < 16; off <<= 1)
#pragma unroll
        for (int mi = 0; mi < 4; mi++)
#pragma unroll
            for (int r = 0; r < 4; r++) rsum[mi][r] += __shfl_xor(rsum[mi][r], off);

    // normalized P -> LDS (re-fragment for PV)
    bf16* P = Pl[wid];
#pragma unroll
    for (int mi = 0; mi < 4; mi++)
#pragma unroll
        for (int r = 0; r < 4; r++) {
            float rinv = 1.0f / rsum[mi][r];
            int row = mi * 16 + lhi * 4 + r;
#pragma unroll
            for (int ni = 0; ni < 4; ni++)
                P[row * 80 + ni * 16 + llo] = (bf16)(s[mi][ni][r] * rinv);
        }

    // --- O = P V ---
    f32x4 o[4][2];
#pragma unroll
    for (int mi = 0; mi < 4; mi++)
#pragma unroll
        for (int ni = 0; ni < 2; ni++) o[mi][ni] = f32x4{0.f, 0.f, 0.f, 0.f};
#pragma unroll
    for (int kc = 0; kc < 2; kc++) {
        bf16x8 pf[4], vf[2];
#pragma unroll
        for (int mi = 0; mi < 4; mi++)
            pf[mi] = *(const bf16x8*)(P + (mi * 16 + llo) * 80 + kc * 32 + lhi * 8);
#pragma unroll
        for (int ni = 0; ni < 2; ni++)
#pragma unroll
            for (int j = 0; j < 8; j++)
                vf[ni][j] = base[(kc * 32 + lhi * 8 + j) * 768 + 512 + h * 32 + ni * 16 + llo];
#pragma unroll
        for (int mi = 0; mi < 4; mi++)
#pragma unroll
            for (int ni = 0; ni < 2; ni++)
                o[mi][ni] =
                    __builtin_amdgcn_mfma_f32_16x16x32_bf16(pf[mi], vf[ni], o[mi][ni], 0, 0, 0);
    }
#pragma unroll
    for (int mi = 0; mi < 4; mi++)
#pragma unroll
        for (int ni = 0; ni < 2; ni++)
#pragma unroll
            for (int r = 0; r < 4; r++) {
                int row = mi * 16 + lhi * 4 + r;
                aout[(size_t)(w * 64 + row) * 256 + h * 32 + ni * 16 + llo] =
                    (bf16)o[mi][ni][r];
            }
}

// ---------------- launcher ----------------
// L3-CHUNKED SCHEDULE:
//  - QKV+attn run in 4 chunks of 8 images (512 windows); QKV goes to a reused
//    50 MB buffer -> attn reads it from L3; QKV never round-trips HBM.
//  - MLP runs in 4 M-quarters (32768 tokens); FC1 writes a reused 67 MB G
//    buffer -> FC2 reads it from L3; only the last quarter's G lines ever
//    write back to HBM.
extern "C" void kernel_launch(void* const* d_in, const int* in_sizes, int n_in,
                              void* d_out, int out_size, void* d_ws, size_t ws_size,
                              hipStream_t stream) {
    const float* x      = (const float*)d_in[0];
    const float* n1g    = (const float*)d_in[1];
    const float* n1b    = (const float*)d_in[2];
    const float* qkv_w  = (const float*)d_in[3];
    const float* qkv_b  = (const float*)d_in[4];
    const float* proj_w = (const float*)d_in[5];
    const float* proj_b = (const float*)d_in[6];
    const float* btab   = (const float*)d_in[7];
    const float* n2g    = (const float*)d_in[8];
    const float* n2b    = (const float*)d_in[9];
    const float* fc1_w  = (const float*)d_in[10];
    const float* fc1_b  = (const float*)d_in[11];
    const float* fc2_w  = (const float*)d_in[12];
    const float* fc2_b  = (const float*)d_in[13];
    float* out = (float*)d_out;
    char* ws = (char*)d_ws;

    // workspace layout (bytes)
    constexpr size_t o_xw   = 0;                    // XW 67MB (dead after QKV chunks)
    constexpr size_t o_qkvb = 67108864ull;          // QKV chunk buf 50MB (reused x4)
    constexpr size_t o_attn = 268435456ull;         // ATTN 67MB, later Hb
    constexpr size_t o_g    = 0;                    // G quarter buf 67MB (reuses XW)
    constexpr size_t o_h    = 268435456ull;         // Hb bf16 reuses ATTN slot
    constexpr size_t o_wq   = 335544320ull;
    constexpr size_t o_wp   = o_wq + 393216;
    constexpr size_t o_w1   = o_wp + 131072;
    constexpr size_t o_w2   = o_w1 + 524288;
    constexpr size_t o_rpb  = o_w2 + 524288;

    bf16* XW    = (bf16*)(ws + o_xw);
    bf16* QKVB  = (bf16*)(ws + o_qkvb);
    bf16* ATTN  = (bf16*)(ws + o_attn);
    bf16* Gbuf  = (bf16*)(ws + o_g);
    bf16* Hb    = (bf16*)(ws + o_h);
    bf16* WQ    = (bf16*)(ws + o_wq);
    bf16* WP    = (bf16*)(ws + o_wp);
    bf16* W1    = (bf16*)(ws + o_w1);
    bf16* W2    = (bf16*)(ws + o_w2);
    float* RPB  = (float*)(ws + o_rpb);

    dim3 blk(256);
    // prep
    transpose_w<<<768, blk, 0, stream>>>(qkv_w, WQ, 256, 768);
    transpose_w<<<256, blk, 0, stream>>>(proj_w, WP, 256, 256);
    transpose_w<<<1024, blk, 0, stream>>>(fc1_w, W1, 256, 1024);
    transpose_w<<<1024, blk, 0, stream>>>(fc2_w, W2, 1024, 256);
    build_rpb<<<128, blk, 0, stream>>>(btab, RPB);

    // LN1 + shift + window partition
    ln_k<1><<<M_TOK / 4, blk, 0, stream>>>(x, n1g, n1b, XW);

    // QKV + attention, 4 chunks of 32768 tokens (8 images / 512 windows each)
    for (int c = 0; c < 4; ++c) {
        const size_t toff = (size_t)c * 32768;
        gemm_k<768, 256, 0><<<1536, blk, 0, stream>>>(XW + toff * 256, WQ, qkv_b,
                                                      QKVB, nullptr, nullptr);
        attn_k<<<1024, blk, 0, stream>>>(QKVB, RPB, ATTN + toff * 256);
    }

    // proj + reverse + unshift + residual -> d_out (x1)
    gemm_k<256, 256, 1><<<2 * 1024, blk, 0, stream>>>(ATTN, WP, proj_b, nullptr, out, x);
    // LN2
    ln_k<0><<<M_TOK / 4, blk, 0, stream>>>(out, n2g, n2b, Hb);

    // MLP, 4 M-quarters with L3-resident G buffer
    for (int q = 0; q < 4; ++q) {
        const size_t toff = (size_t)q * 32768;
        gemm_k<1024, 256, 2><<<2048, blk, 0, stream>>>(Hb + toff * 256, W1, fc1_b,
                                                       Gbuf, nullptr, nullptr);
        gemm_k<256, 1024, 3><<<512, blk, 0, stream>>>(Gbuf, W2, fc2_b, nullptr,
                                                      out + toff * 256, nullptr);
    }
}